// Round 13
// baseline (129.723 us; speedup 1.0000x reference)
//
#include <hip/hip_runtime.h>
#include <hip/hip_bf16.h>
#include <stdint.h>

#define DD 120
#define HD 15
#define LN_EPS 1e-5f

typedef __attribute__((ext_vector_type(8))) short bf16x8;
typedef __attribute__((ext_vector_type(4))) float f32x4;

__device__ __forceinline__ unsigned short f2bf(float f) {
    return __bfloat16_as_ushort(__float2bfloat16(f));
}

// ---- prep: pack weights as MFMA A-fragments with bias folded into k=120 ----
// W1bp: [24 t][4 kk][64 lane][8 e]; A-row n = padded qkv channel t*16+(lane&15)
//       tile t = part*8 + h (pos = part*128 + h*16 + i)
//       k<120: weight; k==120: bias (i<15) / 1.0 marker for V-head0-pad (part==2,h==0,i==15)
// W2bp: [8 t][4 kk][64 lane][8 e]; A-row n = out channel; k = head-padded o-channel;
//       kpad==15 carries out_b (fed by O[15]==1.0)
__global__ void prep_weights(const float* __restrict__ w1, const float* __restrict__ w2,
                             const float* __restrict__ b1, const float* __restrict__ b2,
                             unsigned short* __restrict__ W1bp, unsigned short* __restrict__ W2bp) {
    int idx = blockIdx.x * blockDim.x + threadIdx.x;
    int stride = gridDim.x * blockDim.x;
    for (int p = idx; p < 24 * 4 * 64 * 8; p += stride) {
        int e = p & 7, lane = (p >> 3) & 63, kk = (p >> 9) & 3, t = p >> 11;
        int pos = t * 16 + (lane & 15);
        int part = pos >> 7, rem = pos & 127, h = rem >> 4, i = rem & 15;
        int k = kk * 32 + (lane >> 4) * 8 + e;
        float v = 0.f;
        if (k < DD)        { if (i < HD) v = w1[(part * DD + h * HD + i) * DD + k]; }
        else if (k == DD)  { if (i < HD) v = b1[part * DD + h * HD + i];
                             else if (part == 2 && h == 0) v = 1.0f; }
        W1bp[p] = f2bf(v);
    }
    for (int p = idx; p < 8 * 4 * 64 * 8; p += stride) {
        int e = p & 7, lane = (p >> 3) & 63, kk = (p >> 9) & 3, t = p >> 11;
        int n = t * 16 + (lane & 15);
        int kpad = kk * 32 + (lane >> 4) * 8 + e;
        int i = kpad & 15;
        int h = kpad >> 4;
        float v = 0.f;
        if (n < DD) {
            if (i < HD) v = w2[n * DD + h * HD + i];
            else if (kpad == 15) v = b2[n];
        }
        W2bp[p] = f2bf(v);
    }
}

// ---- fused: 64 locations (128 tokens) per 512-thread WG (8 waves) ----
// R12 structure scaled 2x: waves 0-3 own token-half 0, waves 4-7 own half 1;
// each wave keeps the R12 role (heads {w&3, (w&3)+4} on its half's 4 tiles).
// LDS 64KB -> 2 WG/CU x 8 waves = 16 waves/CU (vs 12 at 256-thr/32KB).
__global__ __launch_bounds__(512, 4) void fused_attn(
    const float* __restrict__ voxel, const float* __restrict__ cnnf,
    const float* __restrict__ gamma, const float* __restrict__ beta,
    const unsigned short* __restrict__ W1bp, const unsigned short* __restrict__ W2bp,
    float* __restrict__ out)
{
    // xs  : [128 tok][128 pos] bf16 swizzled (x)     32768 B
    // obuf: [128 tok][128 pos] bf16 swizzled (O)     32768 B
    // yf  : [128 tok][128 ch]  f32 swizzled — overlays both after B2.5
    __shared__ __align__(16) char smem[65536];
    unsigned short* xs   = (unsigned short*)smem;
    unsigned short* obuf = (unsigned short*)(smem + 32768);
    float* yf = (float*)smem;

    const int tid = threadIdx.x;
    const int wave = tid >> 6, lane = tid & 63;
    const int lrow = lane & 15, lk = lane >> 4;
    const int ww = wave & 3;            // n-split role: heads {ww, ww+4}
    const int g = wave >> 2;            // token half 0/1
    const int r7 = lrow & 7;
    const int tok0 = blockIdx.x * 128;

    // ---- prefetch first two W1 A-tiles (hide under staging) ----
    bf16x8 A[2][4];
    #pragma unroll
    for (int kk = 0; kk < 4; ++kk) {
        A[0][kk] = *(const bf16x8*)(W1bp + ((size_t)(((0 * 8 + ww) * 4 + kk) * 64 + lane)) * 8);
        A[1][kk] = *(const bf16x8*)(W1bp + ((size_t)(((1 * 8 + ww) * 4 + kk) * 64 + lane)) * 8);
    }

    // ---- phase 1: stage x -> bf16 swizzled LDS (128 tokens) ----
    for (int i = tid; i < 128 * 30; i += 512) {
        int r = i / 30, c4 = i % 30;
        int gtok = tok0 + r;
        const float* src = ((gtok & 1) ? cnnf : voxel) + (size_t)(gtok >> 1) * DD + c4 * 4;
        float4 f = *(const float4*)src;
        ushort4 hv;
        hv.x = f2bf(f.x); hv.y = f2bf(f.y); hv.z = f2bf(f.z); hv.w = f2bf(f.w);
        int c8 = c4 >> 1, sub = (c4 & 1) * 8;
        *(ushort4*)((char*)xs + r * 256 + ((c8 ^ (r & 7)) << 4) + sub) = hv;
    }
    if (tid < 128) {   // pad chunk 15: x[120]=1.0 (bias channel), 121..127 = 0
        int r = tid;
        ushort4 p0; p0.x = 0x3F80; p0.y = 0; p0.z = 0; p0.w = 0;
        ushort4 z0; z0.x = 0; z0.y = 0; z0.z = 0; z0.w = 0;
        char* base = (char*)xs + r * 256 + ((15 ^ (r & 7)) << 4);
        *(ushort4*)base = p0;
        *(ushort4*)(base + 8) = z0;
    }
    __syncthreads();   // B1

    // ---- B-frags for this wave's 4 token-tiles (rows g*64 + b*16 + lrow) ----
    bf16x8 bfr[4][4];
    #pragma unroll
    for (int b = 0; b < 4; ++b)
        #pragma unroll
        for (int kk = 0; kk < 4; ++kk) {
            int chunk = kk * 4 + lk;
            int row = g * 64 + b * 16 + lrow;
            bfr[b][kk] = *(const bf16x8*)((const char*)xs + row * 256 + ((chunk ^ r7) << 4));
        }

    // ---- phase 2+3: QKV GEMM + attention, head-sequential ----
    const float scale = 0.25819888974716112567f;   // 1/sqrt(15)
    #pragma unroll
    for (int hh = 0; hh < 2; ++hh) {
        int h = ww + 4 * hh;
        f32x4 acc[3][4];
        __builtin_amdgcn_s_setprio(1);
        #pragma unroll
        for (int part = 0; part < 3; ++part) {
            int u = hh * 3 + part;
            #pragma unroll
            for (int b = 0; b < 4; ++b) {
                f32x4 a = {0.f, 0.f, 0.f, 0.f};
                #pragma unroll
                for (int kk = 0; kk < 4; ++kk)
                    a = __builtin_amdgcn_mfma_f32_16x16x32_bf16(A[u & 1][kk], bfr[b][kk], a, 0, 0, 0);
                acc[part][b] = a;
            }
            if (u + 2 < 6) {   // prefetch tile T[u+2] into the buffer just consumed
                int v = u + 2;
                int t2 = (v % 3) * 8 + (ww + 4 * (v / 3));
                #pragma unroll
                for (int kk = 0; kk < 4; ++kk)
                    A[u & 1][kk] = *(const bf16x8*)(W1bp + ((size_t)((t2 * 4 + kk) * 64 + lane)) * 8);
            }
        }
        __builtin_amdgcn_s_setprio(0);
        #pragma unroll
        for (int b = 0; b < 4; ++b) {
            f32x4 Q = acc[0][b], K = acc[1][b], V = acc[2][b];
            float kn0 = __shfl_xor(K[0], 1), kn1 = __shfl_xor(K[1], 1);
            float kn2 = __shfl_xor(K[2], 1), kn3 = __shfl_xor(K[3], 1);
            float ps = Q[0] * K[0] + Q[1] * K[1] + Q[2] * K[2] + Q[3] * K[3];
            float pn = Q[0] * kn0 + Q[1] * kn1 + Q[2] * kn2 + Q[3] * kn3;
            ps += __shfl_xor(ps, 16); ps += __shfl_xor(ps, 32);
            pn += __shfl_xor(pn, 16); pn += __shfl_xor(pn, 32);
            // softmax over 2 logits == sigmoid of the difference (safe at +/-inf)
            float d = (pn - ps) * scale;
            float p0 = 1.f / (1.f + __expf(d));
            float p1 = 1.f - p0;
            float o0 = p0 * V[0] + p1 * __shfl_xor(V[0], 1);
            float o1 = p0 * V[1] + p1 * __shfl_xor(V[1], 1);
            float o2 = p0 * V[2] + p1 * __shfl_xor(V[2], 1);
            float o3 = p0 * V[3] + p1 * __shfl_xor(V[3], 1);
            unsigned w0 = (unsigned)f2bf(o0) | ((unsigned)f2bf(o1) << 16);
            unsigned w1v = (unsigned)f2bf(o2) | ((unsigned)f2bf(o3) << 16);
            int chunk = 2 * h + (lk >> 1);
            int row = g * 64 + b * 16 + lrow;
            *(uint2*)((char*)obuf + row * 256 + ((chunk ^ r7) << 4) + (lk & 1) * 8)
                = make_uint2(w0, w1v);
        }
    }

    // prefetch this wave's two W2 A-tiles (t = ww, ww+4) before the barrier
    bf16x8 A2[2][4];
    #pragma unroll
    for (int ti = 0; ti < 2; ++ti)
        #pragma unroll
        for (int kk = 0; kk < 4; ++kk)
            A2[ti][kk] = *(const bf16x8*)(W2bp + ((size_t)(((ww + 4 * ti) * 4 + kk) * 64 + lane)) * 8);
    __syncthreads();   // B2

    // ---- phase 4: out projection, n-split over 8 W2 tiles per half; y f32 ----
    {
        bf16x8 ofr[4][4];
        #pragma unroll
        for (int b = 0; b < 4; ++b)
            #pragma unroll
            for (int kk = 0; kk < 4; ++kk) {
                int chunk = kk * 4 + lk;
                int row = g * 64 + b * 16 + lrow;
                ofr[b][kk] = *(const bf16x8*)((const char*)obuf + row * 256 + ((chunk ^ r7) << 4));
            }
        __syncthreads();   // B2.5: all ofr reads done -> xs+obuf reusable as yf
        __builtin_amdgcn_s_setprio(1);
        #pragma unroll
        for (int ti = 0; ti < 2; ++ti) {
            int t = ww + 4 * ti;
            int chunk = 4 * t + lk;            // 16B f32 chunk = channels 16t+4lk..+3
            #pragma unroll
            for (int b = 0; b < 4; ++b) {
                f32x4 a = {0.f, 0.f, 0.f, 0.f};
                #pragma unroll
                for (int kk = 0; kk < 4; ++kk)
                    a = __builtin_amdgcn_mfma_f32_16x16x32_bf16(A2[ti][kk], ofr[b][kk], a, 0, 0, 0);
                int row = g * 64 + b * 16 + lrow;
                *(f32x4*)((char*)yf + row * 512 + ((chunk ^ r7) << 4)) = a;
            }
        }
        __builtin_amdgcn_s_setprio(0);
    }
    __syncthreads();   // B3

    // ---- phase 5: LayerNorm + mean-pool, 8 threads per location (f32 y) ----
    {
        int locl = tid >> 3;          // 0..63
        int s = tid & 7;              // chunk group
        int r0 = 2 * locl, r1 = r0 + 1;
        auto rdf = [&](int r, int c) -> f32x4 {
            return *(const f32x4*)((const char*)yf + r * 512 + ((c ^ (r & 7)) << 4));
        };
        // thread covers channels [8s..8s+7] and [64+8s..64+8s+7] of both rows
        f32x4 v00 = rdf(r0, 2 * s),      v01 = rdf(r0, 2 * s + 1);
        f32x4 v02 = rdf(r0, 16 + 2 * s), v03 = rdf(r0, 16 + 2 * s + 1);
        f32x4 v10 = rdf(r1, 2 * s),      v11 = rdf(r1, 2 * s + 1);
        f32x4 v12 = rdf(r1, 16 + 2 * s), v13 = rdf(r1, 16 + 2 * s + 1);
        float a0[16], a1[16];
        #pragma unroll
        for (int j = 0; j < 4; ++j) {
            a0[j] = v00[j]; a0[4 + j] = v01[j]; a0[8 + j] = v02[j]; a0[12 + j] = v03[j];
            a1[j] = v10[j]; a1[4 + j] = v11[j]; a1[8 + j] = v12[j]; a1[12 + j] = v13[j];
        }
        float sum0 = 0.f, sq0 = 0.f, sum1 = 0.f, sq1 = 0.f;
        #pragma unroll
        for (int j = 0; j < 16; ++j) {   // pad channels (>=120) are exact zeros
            sum0 += a0[j]; sq0 += a0[j] * a0[j];
            sum1 += a1[j]; sq1 += a1[j] * a1[j];
        }
        #pragma unroll
        for (int w2i = 1; w2i < 8; w2i <<= 1) {
            sum0 += __shfl_xor(sum0, w2i); sq0 += __shfl_xor(sq0, w2i);
            sum1 += __shfl_xor(sum1, w2i); sq1 += __shfl_xor(sq1, w2i);
        }
        const float inv = 1.f / 120.f;
        float mu0 = sum0 * inv, mu1 = sum1 * inv;
        float var0 = sq0 * inv - mu0 * mu0, var1 = sq1 * inv - mu1 * mu1;
        float rs0 = rsqrtf(var0 + LN_EPS), rs1 = rsqrtf(var1 + LN_EPS);
        float* op = out + (size_t)(blockIdx.x * 64 + locl) * DD;
        // first 8 channels: c = 8*s (always < 120)
        {
            int c = 8 * s;
            #pragma unroll
            for (int q = 0; q < 2; ++q) {
                f32x4 gm = *(const f32x4*)(gamma + c + 4 * q);
                f32x4 bt = *(const f32x4*)(beta + c + 4 * q);
                float4 o4;
                float z0, z1;
                z0 = (a0[4 * q + 0] - mu0) * rs0; z1 = (a1[4 * q + 0] - mu1) * rs1;
                o4.x = 0.5f * (z0 + z1) * gm[0] + bt[0];
                z0 = (a0[4 * q + 1] - mu0) * rs0; z1 = (a1[4 * q + 1] - mu1) * rs1;
                o4.y = 0.5f * (z0 + z1) * gm[1] + bt[1];
                z0 = (a0[4 * q + 2] - mu0) * rs0; z1 = (a1[4 * q + 2] - mu1) * rs1;
                o4.z = 0.5f * (z0 + z1) * gm[2] + bt[2];
                z0 = (a0[4 * q + 3] - mu0) * rs0; z1 = (a1[4 * q + 3] - mu1) * rs1;
                o4.w = 0.5f * (z0 + z1) * gm[3] + bt[3];
                *(float4*)(op + c + 4 * q) = o4;
            }
        }
        // second 8 channels: c = 64 + 8*s (skip s==7: channels 120..127 are pad)
        if (s < 7) {
            int c = 64 + 8 * s;
            #pragma unroll
            for (int q = 0; q < 2; ++q) {
                f32x4 gm = *(const f32x4*)(gamma + c + 4 * q);
                f32x4 bt = *(const f32x4*)(beta + c + 4 * q);
                float4 o4;
                float z0, z1;
                z0 = (a0[8 + 4 * q + 0] - mu0) * rs0; z1 = (a1[8 + 4 * q + 0] - mu1) * rs1;
                o4.x = 0.5f * (z0 + z1) * gm[0] + bt[0];
                z0 = (a0[8 + 4 * q + 1] - mu0) * rs0; z1 = (a1[8 + 4 * q + 1] - mu1) * rs1;
                o4.y = 0.5f * (z0 + z1) * gm[1] + bt[1];
                z0 = (a0[8 + 4 * q + 2] - mu0) * rs0; z1 = (a1[8 + 4 * q + 2] - mu1) * rs1;
                o4.z = 0.5f * (z0 + z1) * gm[2] + bt[2];
                z0 = (a0[8 + 4 * q + 3] - mu0) * rs0; z1 = (a1[8 + 4 * q + 3] - mu1) * rs1;
                o4.w = 0.5f * (z0 + z1) * gm[3] + bt[3];
                *(float4*)(op + c + 4 * q) = o4;
            }
        }
    }
}

extern "C" void kernel_launch(void* const* d_in, const int* in_sizes, int n_in,
                              void* d_out, int out_size, void* d_ws, size_t ws_size,
                              hipStream_t stream) {
    const float* voxel = (const float*)d_in[0];
    const float* cnnf  = (const float*)d_in[1];
    const float* w1    = (const float*)d_in[2];
    const float* b1    = (const float*)d_in[3];
    const float* w2    = (const float*)d_in[4];
    const float* b2    = (const float*)d_in[5];
    const float* gamma = (const float*)d_in[6];
    const float* beta  = (const float*)d_in[7];
    float* out = (float*)d_out;

    unsigned short* W1bp = (unsigned short*)d_ws;                    // 24*4*64*8*2 = 98304 B
    unsigned short* W2bp = (unsigned short*)((char*)d_ws + 98304);   // 8*4*64*8*2  = 32768 B

    int nloc = in_sizes[0] / DD;   // 131072 locations
    prep_weights<<<128, 256, 0, stream>>>(w1, w2, b1, b2, W1bp, W2bp);
    fused_attn<<<nloc / 64, 512, 0, stream>>>(voxel, cnnf, gamma, beta, W1bp, W2bp, out);
}

// Round 14
// 79.675 us; speedup vs baseline: 1.6282x; 1.6282x over previous
//
#include <hip/hip_runtime.h>
#include <hip/hip_bf16.h>
#include <stdint.h>

#define DD 120
#define HD 15
#define LN_EPS 1e-5f

typedef __attribute__((ext_vector_type(8))) short bf16x8;
typedef __attribute__((ext_vector_type(4))) float f32x4;

__device__ __forceinline__ unsigned short f2bf(float f) {
    return __bfloat16_as_ushort(__float2bfloat16(f));
}

// ---- prep: pack weights as MFMA A-fragments with bias folded into k=120 ----
// W1bp: [24 t][4 kk][64 lane][8 e]; A-row n = padded qkv channel t*16+(lane&15)
//       tile t = part*8 + h (pos = part*128 + h*16 + i)
//       k<120: weight; k==120: bias (i<15) / 1.0 marker for V-head0-pad (part==2,h==0,i==15)
// W2bp: [8 t][4 kk][64 lane][8 e]; A-row n = out channel; k = head-padded o-channel;
//       kpad==15 carries out_b (fed by O[15]==1.0)
__global__ void prep_weights(const float* __restrict__ w1, const float* __restrict__ w2,
                             const float* __restrict__ b1, const float* __restrict__ b2,
                             unsigned short* __restrict__ W1bp, unsigned short* __restrict__ W2bp) {
    int idx = blockIdx.x * blockDim.x + threadIdx.x;
    int stride = gridDim.x * blockDim.x;
    for (int p = idx; p < 24 * 4 * 64 * 8; p += stride) {
        int e = p & 7, lane = (p >> 3) & 63, kk = (p >> 9) & 3, t = p >> 11;
        int pos = t * 16 + (lane & 15);
        int part = pos >> 7, rem = pos & 127, h = rem >> 4, i = rem & 15;
        int k = kk * 32 + (lane >> 4) * 8 + e;
        float v = 0.f;
        if (k < DD)        { if (i < HD) v = w1[(part * DD + h * HD + i) * DD + k]; }
        else if (k == DD)  { if (i < HD) v = b1[part * DD + h * HD + i];
                             else if (part == 2 && h == 0) v = 1.0f; }
        W1bp[p] = f2bf(v);
    }
    for (int p = idx; p < 8 * 4 * 64 * 8; p += stride) {
        int e = p & 7, lane = (p >> 3) & 63, kk = (p >> 9) & 3, t = p >> 11;
        int n = t * 16 + (lane & 15);
        int kpad = kk * 32 + (lane >> 4) * 8 + e;
        int i = kpad & 15;
        int h = kpad >> 4;
        float v = 0.f;
        if (n < DD) {
            if (i < HD) v = w2[n * DD + h * HD + i];
            else if (kpad == 15) v = b2[n];
        }
        W2bp[p] = f2bf(v);
    }
}

// ---- fused: 32 locations (64 tokens) per 256-thread WG; 4-way n-split ----
// R12 structure (known-good 81.1us) with B2.5 removed via LDS re-layout:
// [xs 16K][extra 16K][obuf 16K]; yf f32 overlays xs+extra (0..32K) and never
// touches obuf, so phase-4 writes need no extra barrier against ofr reads.
// 48KB x 3 WG/CU = 144KB <= 160KB: occupancy class unchanged.
__global__ __launch_bounds__(256, 3) void fused_attn(
    const float* __restrict__ voxel, const float* __restrict__ cnnf,
    const float* __restrict__ gamma, const float* __restrict__ beta,
    const unsigned short* __restrict__ W1bp, const unsigned short* __restrict__ W2bp,
    float* __restrict__ out)
{
    __shared__ __align__(16) char smem[49152];
    unsigned short* xs   = (unsigned short*)smem;            // [64][128] bf16 swizzled
    unsigned short* obuf = (unsigned short*)(smem + 32768);  // [64][128] bf16 swizzled
    float* yf = (float*)smem;                                // [64][128] f32 swizzled (xs+extra)

    const int tid = threadIdx.x;
    const int wave = tid >> 6, lane = tid & 63;
    const int lrow = lane & 15, lk = lane >> 4;
    const int w = wave;                 // n-split: this wave owns heads {w, w+4}
    const int r7 = lrow & 7;
    const int tok0 = blockIdx.x * 64;

    // ---- prefetch first two W1 A-tiles (hide under staging) ----
    bf16x8 A[2][4];
    #pragma unroll
    for (int kk = 0; kk < 4; ++kk) {
        A[0][kk] = *(const bf16x8*)(W1bp + ((size_t)(((0 * 8 + w) * 4 + kk) * 64 + lane)) * 8);
        A[1][kk] = *(const bf16x8*)(W1bp + ((size_t)(((1 * 8 + w) * 4 + kk) * 64 + lane)) * 8);
    }

    // ---- phase 1: stage x -> bf16 swizzled LDS (64 tokens) ----
    for (int i = tid; i < 64 * 30; i += 256) {
        int r = i / 30, c4 = i % 30;
        int gtok = tok0 + r;
        const float* src = ((gtok & 1) ? cnnf : voxel) + (size_t)(gtok >> 1) * DD + c4 * 4;
        float4 f = *(const float4*)src;
        ushort4 hv;
        hv.x = f2bf(f.x); hv.y = f2bf(f.y); hv.z = f2bf(f.z); hv.w = f2bf(f.w);
        int c8 = c4 >> 1, sub = (c4 & 1) * 8;
        *(ushort4*)((char*)xs + r * 256 + ((c8 ^ (r & 7)) << 4) + sub) = hv;
    }
    if (tid < 64) {   // pad chunk 15: x[120]=1.0 (bias channel), 121..127 = 0
        int r = tid;
        ushort4 p0; p0.x = 0x3F80; p0.y = 0; p0.z = 0; p0.w = 0;
        ushort4 z0; z0.x = 0; z0.y = 0; z0.z = 0; z0.w = 0;
        char* base = (char*)xs + r * 256 + ((15 ^ (r & 7)) << 4);
        *(ushort4*)base = p0;
        *(ushort4*)(base + 8) = z0;
    }
    __syncthreads();   // B1

    // ---- B-frags for all 4 token-tiles into registers (xs dead after this) ----
    bf16x8 bfr[4][4];
    #pragma unroll
    for (int b = 0; b < 4; ++b)
        #pragma unroll
        for (int kk = 0; kk < 4; ++kk) {
            int chunk = kk * 4 + lk;
            bfr[b][kk] = *(const bf16x8*)((const char*)xs + (b * 16 + lrow) * 256 + ((chunk ^ r7) << 4));
        }

    // ---- phase 2+3: QKV GEMM + attention, head-sequential ----
    const float scale = 0.25819888974716112567f;   // 1/sqrt(15)
    #pragma unroll
    for (int hh = 0; hh < 2; ++hh) {
        int h = w + 4 * hh;
        f32x4 acc[3][4];
        __builtin_amdgcn_s_setprio(1);
        #pragma unroll
        for (int part = 0; part < 3; ++part) {
            int u = hh * 3 + part;
            #pragma unroll
            for (int b = 0; b < 4; ++b) {
                f32x4 a = {0.f, 0.f, 0.f, 0.f};
                #pragma unroll
                for (int kk = 0; kk < 4; ++kk)
                    a = __builtin_amdgcn_mfma_f32_16x16x32_bf16(A[u & 1][kk], bfr[b][kk], a, 0, 0, 0);
                acc[part][b] = a;
            }
            if (u + 2 < 6) {   // prefetch tile T[u+2] into the buffer just consumed
                int v = u + 2;
                int t2 = (v % 3) * 8 + (w + 4 * (v / 3));
                #pragma unroll
                for (int kk = 0; kk < 4; ++kk)
                    A[u & 1][kk] = *(const bf16x8*)(W1bp + ((size_t)((t2 * 4 + kk) * 64 + lane)) * 8);
            }
        }
        __builtin_amdgcn_s_setprio(0);
        #pragma unroll
        for (int b = 0; b < 4; ++b) {
            f32x4 Q = acc[0][b], K = acc[1][b], V = acc[2][b];
            float kn0 = __shfl_xor(K[0], 1), kn1 = __shfl_xor(K[1], 1);
            float kn2 = __shfl_xor(K[2], 1), kn3 = __shfl_xor(K[3], 1);
            float ps = Q[0] * K[0] + Q[1] * K[1] + Q[2] * K[2] + Q[3] * K[3];
            float pn = Q[0] * kn0 + Q[1] * kn1 + Q[2] * kn2 + Q[3] * kn3;
            ps += __shfl_xor(ps, 16); ps += __shfl_xor(ps, 32);
            pn += __shfl_xor(pn, 16); pn += __shfl_xor(pn, 32);
            // softmax over 2 logits == sigmoid of the difference (safe at +/-inf)
            float d = (pn - ps) * scale;
            float p0 = 1.f / (1.f + __expf(d));
            float p1 = 1.f - p0;
            float o0 = p0 * V[0] + p1 * __shfl_xor(V[0], 1);
            float o1 = p0 * V[1] + p1 * __shfl_xor(V[1], 1);
            float o2 = p0 * V[2] + p1 * __shfl_xor(V[2], 1);
            float o3 = p0 * V[3] + p1 * __shfl_xor(V[3], 1);
            unsigned w0 = (unsigned)f2bf(o0) | ((unsigned)f2bf(o1) << 16);
            unsigned w1v = (unsigned)f2bf(o2) | ((unsigned)f2bf(o3) << 16);
            int chunk = 2 * h + (lk >> 1);
            *(uint2*)((char*)obuf + (b * 16 + lrow) * 256 + ((chunk ^ r7) << 4) + (lk & 1) * 8)
                = make_uint2(w0, w1v);
        }
    }

    // prefetch this wave's two W2 A-tiles (t = w, w+4) before the barrier
    bf16x8 A2[2][4];
    #pragma unroll
    for (int ti = 0; ti < 2; ++ti)
        #pragma unroll
        for (int kk = 0; kk < 4; ++kk)
            A2[ti][kk] = *(const bf16x8*)(W2bp + ((size_t)(((w + 4 * ti) * 4 + kk) * 64 + lane)) * 8);
    __syncthreads();   // B2: obuf visible

    // ---- phase 4: out projection; yf writes don't touch obuf -> no extra barrier ----
    {
        bf16x8 ofr[4][4];
        #pragma unroll
        for (int b = 0; b < 4; ++b)
            #pragma unroll
            for (int kk = 0; kk < 4; ++kk) {
                int chunk = kk * 4 + lk;
                ofr[b][kk] = *(const bf16x8*)((const char*)obuf + (b * 16 + lrow) * 256 + ((chunk ^ r7) << 4));
            }
        __builtin_amdgcn_s_setprio(1);
        #pragma unroll
        for (int ti = 0; ti < 2; ++ti) {
            int t = w + 4 * ti;
            int chunk = 4 * t + lk;            // 16B f32 chunk = channels 16t+4lk..+3
            #pragma unroll
            for (int b = 0; b < 4; ++b) {
                f32x4 a = {0.f, 0.f, 0.f, 0.f};
                #pragma unroll
                for (int kk = 0; kk < 4; ++kk)
                    a = __builtin_amdgcn_mfma_f32_16x16x32_bf16(A2[ti][kk], ofr[b][kk], a, 0, 0, 0);
                int row = b * 16 + lrow;
                *(f32x4*)((char*)yf + row * 512 + ((chunk ^ r7) << 4)) = a;
            }
        }
        __builtin_amdgcn_s_setprio(0);
    }
    __syncthreads();   // B3: yf visible

    // ---- phase 5: LayerNorm + mean-pool, 8 threads per location (f32 y) ----
    {
        int locl = tid >> 3;          // 0..31
        int s = tid & 7;              // chunk group
        int r0 = 2 * locl, r1 = r0 + 1;
        auto rdf = [&](int r, int c) -> f32x4 {
            return *(const f32x4*)((const char*)yf + r * 512 + ((c ^ (r & 7)) << 4));
        };
        // thread covers channels [8s..8s+7] and [64+8s..64+8s+7] of both rows
        f32x4 v00 = rdf(r0, 2 * s),      v01 = rdf(r0, 2 * s + 1);
        f32x4 v02 = rdf(r0, 16 + 2 * s), v03 = rdf(r0, 16 + 2 * s + 1);
        f32x4 v10 = rdf(r1, 2 * s),      v11 = rdf(r1, 2 * s + 1);
        f32x4 v12 = rdf(r1, 16 + 2 * s), v13 = rdf(r1, 16 + 2 * s + 1);
        float a0[16], a1[16];
        #pragma unroll
        for (int j = 0; j < 4; ++j) {
            a0[j] = v00[j]; a0[4 + j] = v01[j]; a0[8 + j] = v02[j]; a0[12 + j] = v03[j];
            a1[j] = v10[j]; a1[4 + j] = v11[j]; a1[8 + j] = v12[j]; a1[12 + j] = v13[j];
        }
        float sum0 = 0.f, sq0 = 0.f, sum1 = 0.f, sq1 = 0.f;
        #pragma unroll
        for (int j = 0; j < 16; ++j) {   // pad channels (>=120) are exact zeros
            sum0 += a0[j]; sq0 += a0[j] * a0[j];
            sum1 += a1[j]; sq1 += a1[j] * a1[j];
        }
        #pragma unroll
        for (int ww = 1; ww < 8; ww <<= 1) {
            sum0 += __shfl_xor(sum0, ww); sq0 += __shfl_xor(sq0, ww);
            sum1 += __shfl_xor(sum1, ww); sq1 += __shfl_xor(sq1, ww);
        }
        const float inv = 1.f / 120.f;
        float mu0 = sum0 * inv, mu1 = sum1 * inv;
        float var0 = sq0 * inv - mu0 * mu0, var1 = sq1 * inv - mu1 * mu1;
        float rs0 = rsqrtf(var0 + LN_EPS), rs1 = rsqrtf(var1 + LN_EPS);
        float* op = out + (size_t)(blockIdx.x * 32 + locl) * DD;
        // first 8 channels: c = 8*s (always < 120)
        {
            int c = 8 * s;
            #pragma unroll
            for (int q = 0; q < 2; ++q) {
                f32x4 gm = *(const f32x4*)(gamma + c + 4 * q);
                f32x4 bt = *(const f32x4*)(beta + c + 4 * q);
                float4 o4;
                float z0, z1;
                z0 = (a0[4 * q + 0] - mu0) * rs0; z1 = (a1[4 * q + 0] - mu1) * rs1;
                o4.x = 0.5f * (z0 + z1) * gm[0] + bt[0];
                z0 = (a0[4 * q + 1] - mu0) * rs0; z1 = (a1[4 * q + 1] - mu1) * rs1;
                o4.y = 0.5f * (z0 + z1) * gm[1] + bt[1];
                z0 = (a0[4 * q + 2] - mu0) * rs0; z1 = (a1[4 * q + 2] - mu1) * rs1;
                o4.z = 0.5f * (z0 + z1) * gm[2] + bt[2];
                z0 = (a0[4 * q + 3] - mu0) * rs0; z1 = (a1[4 * q + 3] - mu1) * rs1;
                o4.w = 0.5f * (z0 + z1) * gm[3] + bt[3];
                *(float4*)(op + c + 4 * q) = o4;
            }
        }
        // second 8 channels: c = 64 + 8*s (skip s==7: channels 120..127 are pad)
        if (s < 7) {
            int c = 64 + 8 * s;
            #pragma unroll
            for (int q = 0; q < 2; ++q) {
                f32x4 gm = *(const f32x4*)(gamma + c + 4 * q);
                f32x4 bt = *(const f32x4*)(beta + c + 4 * q);
                float4 o4;
                float z0, z1;
                z0 = (a0[8 + 4 * q + 0] - mu0) * rs0; z1 = (a1[8 + 4 * q + 0] - mu1) * rs1;
                o4.x = 0.5f * (z0 + z1) * gm[0] + bt[0];
                z0 = (a0[8 + 4 * q + 1] - mu0) * rs0; z1 = (a1[8 + 4 * q + 1] - mu1) * rs1;
                o4.y = 0.5f * (z0 + z1) * gm[1] + bt[1];
                z0 = (a0[8 + 4 * q + 2] - mu0) * rs0; z1 = (a1[8 + 4 * q + 2] - mu1) * rs1;
                o4.z = 0.5f * (z0 + z1) * gm[2] + bt[2];
                z0 = (a0[8 + 4 * q + 3] - mu0) * rs0; z1 = (a1[8 + 4 * q + 3] - mu1) * rs1;
                o4.w = 0.5f * (z0 + z1) * gm[3] + bt[3];
                *(float4*)(op + c + 4 * q) = o4;
            }
        }
    }
}

extern "C" void kernel_launch(void* const* d_in, const int* in_sizes, int n_in,
                              void* d_out, int out_size, void* d_ws, size_t ws_size,
                              hipStream_t stream) {
    const float* voxel = (const float*)d_in[0];
    const float* cnnf  = (const float*)d_in[1];
    const float* w1    = (const float*)d_in[2];
    const float* b1    = (const float*)d_in[3];
    const float* w2    = (const float*)d_in[4];
    const float* b2    = (const float*)d_in[5];
    const float* gamma = (const float*)d_in[6];
    const float* beta  = (const float*)d_in[7];
    float* out = (float*)d_out;

    unsigned short* W1bp = (unsigned short*)d_ws;                    // 24*4*64*8*2 = 98304 B
    unsigned short* W2bp = (unsigned short*)((char*)d_ws + 98304);   // 8*4*64*8*2  = 32768 B

    int nloc = in_sizes[0] / DD;   // 131072 locations
    prep_weights<<<128, 256, 0, stream>>>(w1, w2, b1, b2, W1bp, W2bp);
    fused_attn<<<nloc / 32, 256, 0, stream>>>(voxel, cnnf, gamma, beta, W1bp, W2bp, out);
}